// Round 7
// baseline (735.580 us; speedup 1.0000x reference)
//
#include <hip/hip_runtime.h>

#define N_USERS 100000
#define N_ITEMS 50000
#define N_NODES 150000
#define EMBED 64
#define N_LAYERS 3

#define BSH 8                                   // log2(rows per bucket)
#define BROWS 256                               // rows per bucket
#define NB ((N_NODES + BROWS - 1) / BROWS)      // 586 buckets
#define CAP 9216                                // mean 8192 + ~11 sigma
#define PCHUNK 4096                             // edges per partition WG
#define COLMASK 0x3FFFF                         // 18 bits for col (N_NODES<2^18)

// ---------------------------------------------------------------------------
// init: ego0 = concat(u_emb + u_emb_pre, i_emb + i_emb_pre); acc = ego0
// ---------------------------------------------------------------------------
__global__ void lgcn_init(const float* __restrict__ u, const float* __restrict__ it,
                          const float* __restrict__ up, const float* __restrict__ ip,
                          float* __restrict__ ego, float* __restrict__ acc) {
    int idx = blockIdx.x * blockDim.x + threadIdx.x;  // float4 index
    const int total = N_NODES * EMBED / 4;
    if (idx >= total) return;
    const int uCount = N_USERS * EMBED / 4;
    float4 v;
    if (idx < uCount) {
        float4 a = reinterpret_cast<const float4*>(u)[idx];
        float4 b = reinterpret_cast<const float4*>(up)[idx];
        v = make_float4(a.x + b.x, a.y + b.y, a.z + b.z, a.w + b.w);
    } else {
        int j = idx - uCount;
        float4 a = reinterpret_cast<const float4*>(it)[j];
        float4 b = reinterpret_cast<const float4*>(ip)[j];
        v = make_float4(a.x + b.x, a.y + b.y, a.z + b.z, a.w + b.w);
    }
    reinterpret_cast<float4*>(ego)[idx] = v;
    reinterpret_cast<float4*>(acc)[idx] = v;
}

// ---------------------------------------------------------------------------
// cursor init: fill[b] = b * CAP
// ---------------------------------------------------------------------------
__global__ void lgcn_fill_init(int* __restrict__ fill) {
    int b = blockIdx.x * blockDim.x + threadIdx.x;
    if (b < NB) fill[b] = b * CAP;
}

// ---------------------------------------------------------------------------
// partition: scatter edges into fixed-capacity bucket regions of pcvp,
// packed int2{ (rowLocal<<18)|col , bits(val) }.
// LDS chunk-histogram -> one global cursor reservation per bucket per WG.
// ---------------------------------------------------------------------------
__global__ void lgcn_partition(const int* __restrict__ rows, const int* __restrict__ cols,
                               const float* __restrict__ vals, int* __restrict__ fill,
                               int2* __restrict__ pcvp, int nnz) {
    __shared__ int lcnt[NB];
    __shared__ int lbase[NB];
    int c0 = blockIdx.x * PCHUNK;
    int cend = min(c0 + PCHUNK, nnz);
    for (int b = threadIdx.x; b < NB; b += blockDim.x) lcnt[b] = 0;
    __syncthreads();
    for (int e = c0 + threadIdx.x; e < cend; e += blockDim.x)
        atomicAdd(&lcnt[rows[e] >> BSH], 1);
    __syncthreads();
    for (int b = threadIdx.x; b < NB; b += blockDim.x) {
        int c = lcnt[b];
        lbase[b] = c ? atomicAdd(&fill[b], c) : 0;
        lcnt[b] = 0;  // reuse as intra-WG cursor
    }
    __syncthreads();
    for (int e = c0 + threadIdx.x; e < cend; e += blockDim.x) {
        int r = rows[e];
        int b = r >> BSH;
        int pos = lbase[b] + atomicAdd(&lcnt[b], 1);
        pos = min(pos, (b + 1) * CAP - 1);  // memory-safety clamp (never hit)
        pcvp[pos] = make_int2(((r & (BROWS - 1)) << 18) | cols[e], __float_as_int(vals[e]));
    }
}

// ---------------------------------------------------------------------------
// ebase: exclusive scan of realized bucket counts -> global edge base;
// also writes rowptr[N_NODES] = nnz. One block, 1024 threads (NB=586 fits).
// ---------------------------------------------------------------------------
__global__ __launch_bounds__(1024) void lgcn_ebase(const int* __restrict__ fill,
                                                   int* __restrict__ ebase,
                                                   int* __restrict__ rowptr, int nnz) {
    __shared__ int sm[1024];
    int c = (threadIdx.x < NB) ? (fill[threadIdx.x] - threadIdx.x * CAP) : 0;
    sm[threadIdx.x] = c;
    __syncthreads();
    for (int off = 1; off < 1024; off <<= 1) {
        int t = (threadIdx.x >= (unsigned)off) ? sm[threadIdx.x - off] : 0;
        __syncthreads();
        sm[threadIdx.x] += t;
        __syncthreads();
    }
    if (threadIdx.x < NB) ebase[threadIdx.x] = sm[threadIdx.x] - c;
    if (threadIdx.x == 0) rowptr[N_NODES] = nnz;
}

// ---------------------------------------------------------------------------
// bsort: one WG (256 thr) per 256-row bucket. LDS histogram of rowLocal,
// LDS scan -> rowptr + LDS cursors, then scatter (col,val) to exact
// row-sorted positions (64 KB L2-local window per WG).
// ---------------------------------------------------------------------------
__global__ __launch_bounds__(BROWS) void lgcn_bsort(const int2* __restrict__ pcvp,
                                                    const int* __restrict__ fill,
                                                    const int* __restrict__ ebase,
                                                    int* __restrict__ rowptr,
                                                    int2* __restrict__ cv) {
    __shared__ int sm[BROWS];
    __shared__ int cur[BROWS];
    int b = blockIdx.x;
    int beg = b * CAP;
    int end = min(fill[b], beg + CAP);
    sm[threadIdx.x] = 0;
    __syncthreads();
    for (int i = beg + threadIdx.x; i < end; i += BROWS)
        atomicAdd(&sm[((unsigned)pcvp[i].x) >> 18], 1);
    __syncthreads();
    int c = sm[threadIdx.x];
    for (int off = 1; off < BROWS; off <<= 1) {
        int t = (threadIdx.x >= (unsigned)off) ? sm[threadIdx.x - off] : 0;
        __syncthreads();
        sm[threadIdx.x] += t;
        __syncthreads();
    }
    int eb = ebase[b];
    int excl = sm[threadIdx.x] - c;
    cur[threadIdx.x] = eb + excl;
    int node = b * BROWS + (int)threadIdx.x;
    if (node < N_NODES) rowptr[node] = eb + excl;
    __syncthreads();
    for (int i = beg + threadIdx.x; i < end; i += BROWS) {
        int2 p = pcvp[i];
        int rl = ((unsigned)p.x) >> 18;
        int pos = atomicAdd(&cur[rl], 1);
        cv[pos] = make_int2(p.x & COLMASK, p.y);
    }
}

// ---------------------------------------------------------------------------
// CSR SpMM: 16 lanes per row (float4 per lane), 4 rows per wave.
// Each 16-lane group walks its row's edges with predicated unroll-8 float4
// gathers (8 KB of gather bytes in flight per wave). Fused acc update.
// ---------------------------------------------------------------------------
template <bool WRITE_EGO>
__global__ void lgcn_spmm_csr(const int* __restrict__ rowptr, const int2* __restrict__ cv,
                              const float* __restrict__ x, float* __restrict__ ego_out,
                              float* __restrict__ acc, float scale) {
    int lane = threadIdx.x & 63;
    int grp  = lane >> 4;          // 0..3: which row within the wave
    int sub  = lane & 15;          // dim slice: floats [4*sub, 4*sub+4)
    int wid  = threadIdx.x >> 6;
    int row  = blockIdx.x * 16 + wid * 4 + grp;
    if (row >= N_NODES) return;

    int beg = rowptr[row];
    int end = rowptr[row + 1];
    int lim = end - 1;
    float4 s = make_float4(0.f, 0.f, 0.f, 0.f);

    for (int e = beg; e < end; e += 8) {
#pragma unroll
        for (int k = 0; k < 8; ++k) {
            int idx = min(e + k, lim);
            int2 p = cv[idx];
            float4 xr = *reinterpret_cast<const float4*>(x + (size_t)p.x * EMBED + sub * 4);
            float v = (e + k <= lim) ? __int_as_float(p.y) : 0.f;
            s.x += v * xr.x;
            s.y += v * xr.y;
            s.z += v * xr.z;
            s.w += v * xr.w;
        }
    }

    size_t o = (size_t)row * EMBED + sub * 4;
    if (WRITE_EGO) *reinterpret_cast<float4*>(ego_out + o) = s;
    float4 a = *reinterpret_cast<const float4*>(acc + o);
    a.x = (a.x + s.x) * scale;
    a.y = (a.y + s.y) * scale;
    a.z = (a.z + s.z) * scale;
    a.w = (a.w + s.w) * scale;
    *reinterpret_cast<float4*>(acc + o) = a;
}

extern "C" void kernel_launch(void* const* d_in, const int* in_sizes, int n_in,
                              void* d_out, int out_size, void* d_ws, size_t ws_size,
                              hipStream_t stream) {
    const int*   rows = (const int*)d_in[0];
    const int*   cols = (const int*)d_in[1];
    const float* vals = (const float*)d_in[2];
    const float* u    = (const float*)d_in[3];
    const float* it   = (const float*)d_in[4];
    const float* up   = (const float*)d_in[5];
    const float* ip   = (const float*)d_in[6];
    const int nnz = in_sizes[0];

    float* acc = (float*)d_out;

    // workspace layout (~159 MB)
    float* ego0   = (float*)d_ws;                               // 38.4 MB
    float* ego1   = ego0 + (size_t)N_NODES * EMBED;             // 38.4 MB
    int2*  cv     = (int2*)(ego1 + (size_t)N_NODES * EMBED);    // nnz*8 = 38.4 MB
    int2*  pcvp   = cv + nnz;                                   // NB*CAP*8 = 43.2 MB
    int*   fill   = (int*)(pcvp + (size_t)NB * CAP);            // NB
    int*   ebase  = fill + NB;                                  // NB
    int*   rowptr = ebase + NB;                                 // N_NODES+1

    const int tpb = 256;
    const int totalVec = N_NODES * EMBED / 4;

    lgcn_init<<<(totalVec + tpb - 1) / tpb, tpb, 0, stream>>>(u, it, up, ip, ego0, acc);
    lgcn_fill_init<<<(NB + tpb - 1) / tpb, tpb, 0, stream>>>(fill);
    lgcn_partition<<<(nnz + PCHUNK - 1) / PCHUNK, tpb, 0, stream>>>(
        rows, cols, vals, fill, pcvp, nnz);
    lgcn_ebase<<<1, 1024, 0, stream>>>(fill, ebase, rowptr, nnz);
    lgcn_bsort<<<NB, BROWS, 0, stream>>>(pcvp, fill, ebase, rowptr, cv);

    // 16 rows per block (4 waves x 4 rows); 150000 = 9375 * 16 exactly
    const int spmmBlocks = (N_NODES + 15) / 16;

    lgcn_spmm_csr<true><<<spmmBlocks, tpb, 0, stream>>>(rowptr, cv, ego0, ego1, acc, 1.0f);
    lgcn_spmm_csr<true><<<spmmBlocks, tpb, 0, stream>>>(rowptr, cv, ego1, ego0, acc, 1.0f);
    lgcn_spmm_csr<false><<<spmmBlocks, tpb, 0, stream>>>(rowptr, cv, ego0, nullptr, acc,
                                                         1.0f / (N_LAYERS + 1));
}

// Round 8
// 716.779 us; speedup vs baseline: 1.0262x; 1.0262x over previous
//
#include <hip/hip_runtime.h>

#define N_USERS 100000
#define N_ITEMS 50000
#define N_NODES 150000
#define EMBED 64
#define N_LAYERS 3

#define BSH 8                                   // log2(rows per bucket)
#define BROWS 256                               // rows per bucket
#define NB ((N_NODES + BROWS - 1) / BROWS)      // 586 buckets
#define CAP 9216                                // mean 8192 + ~11 sigma
#define PCHUNK 4096                             // edges per partition WG
#define COLMASK 0x3FFFF                         // 18 bits for col (N_NODES<2^18)
#define UNR 16                                  // gathers in flight per wave

// ---------------------------------------------------------------------------
// init: ego0 = concat(u_emb + u_emb_pre, i_emb + i_emb_pre); acc = ego0
// ---------------------------------------------------------------------------
__global__ void lgcn_init(const float* __restrict__ u, const float* __restrict__ it,
                          const float* __restrict__ up, const float* __restrict__ ip,
                          float* __restrict__ ego, float* __restrict__ acc) {
    int idx = blockIdx.x * blockDim.x + threadIdx.x;  // float4 index
    const int total = N_NODES * EMBED / 4;
    if (idx >= total) return;
    const int uCount = N_USERS * EMBED / 4;
    float4 v;
    if (idx < uCount) {
        float4 a = reinterpret_cast<const float4*>(u)[idx];
        float4 b = reinterpret_cast<const float4*>(up)[idx];
        v = make_float4(a.x + b.x, a.y + b.y, a.z + b.z, a.w + b.w);
    } else {
        int j = idx - uCount;
        float4 a = reinterpret_cast<const float4*>(it)[j];
        float4 b = reinterpret_cast<const float4*>(ip)[j];
        v = make_float4(a.x + b.x, a.y + b.y, a.z + b.z, a.w + b.w);
    }
    reinterpret_cast<float4*>(ego)[idx] = v;
    reinterpret_cast<float4*>(acc)[idx] = v;
}

// ---------------------------------------------------------------------------
// cursor init: fill[b] = b * CAP
// ---------------------------------------------------------------------------
__global__ void lgcn_fill_init(int* __restrict__ fill) {
    int b = blockIdx.x * blockDim.x + threadIdx.x;
    if (b < NB) fill[b] = b * CAP;
}

// ---------------------------------------------------------------------------
// partition: scatter edges into fixed-capacity bucket regions of pcvp,
// packed int2{ (rowLocal<<18)|col , bits(val) }.
// ---------------------------------------------------------------------------
__global__ void lgcn_partition(const int* __restrict__ rows, const int* __restrict__ cols,
                               const float* __restrict__ vals, int* __restrict__ fill,
                               int2* __restrict__ pcvp, int nnz) {
    __shared__ int lcnt[NB];
    __shared__ int lbase[NB];
    int c0 = blockIdx.x * PCHUNK;
    int cend = min(c0 + PCHUNK, nnz);
    for (int b = threadIdx.x; b < NB; b += blockDim.x) lcnt[b] = 0;
    __syncthreads();
    for (int e = c0 + threadIdx.x; e < cend; e += blockDim.x)
        atomicAdd(&lcnt[rows[e] >> BSH], 1);
    __syncthreads();
    for (int b = threadIdx.x; b < NB; b += blockDim.x) {
        int c = lcnt[b];
        lbase[b] = c ? atomicAdd(&fill[b], c) : 0;
        lcnt[b] = 0;  // reuse as intra-WG cursor
    }
    __syncthreads();
    for (int e = c0 + threadIdx.x; e < cend; e += blockDim.x) {
        int r = rows[e];
        int b = r >> BSH;
        int pos = lbase[b] + atomicAdd(&lcnt[b], 1);
        pos = min(pos, (b + 1) * CAP - 1);  // memory-safety clamp (never hit)
        pcvp[pos] = make_int2(((r & (BROWS - 1)) << 18) | cols[e], __float_as_int(vals[e]));
    }
}

// ---------------------------------------------------------------------------
// ebase: exclusive scan of realized bucket counts -> global edge base.
// ---------------------------------------------------------------------------
__global__ __launch_bounds__(1024) void lgcn_ebase(const int* __restrict__ fill,
                                                   int* __restrict__ ebase,
                                                   int* __restrict__ rowptr, int nnz) {
    __shared__ int sm[1024];
    int c = (threadIdx.x < NB) ? (fill[threadIdx.x] - threadIdx.x * CAP) : 0;
    sm[threadIdx.x] = c;
    __syncthreads();
    for (int off = 1; off < 1024; off <<= 1) {
        int t = (threadIdx.x >= (unsigned)off) ? sm[threadIdx.x - off] : 0;
        __syncthreads();
        sm[threadIdx.x] += t;
        __syncthreads();
    }
    if (threadIdx.x < NB) ebase[threadIdx.x] = sm[threadIdx.x] - c;
    if (threadIdx.x == 0) rowptr[N_NODES] = nnz;
}

// ---------------------------------------------------------------------------
// bsort: one WG per 256-row bucket; LDS hist + scan -> rowptr; scatter
// (col,val) to exact row-sorted positions.
// ---------------------------------------------------------------------------
__global__ __launch_bounds__(BROWS) void lgcn_bsort(const int2* __restrict__ pcvp,
                                                    const int* __restrict__ fill,
                                                    const int* __restrict__ ebase,
                                                    int* __restrict__ rowptr,
                                                    int2* __restrict__ cv) {
    __shared__ int sm[BROWS];
    __shared__ int cur[BROWS];
    int b = blockIdx.x;
    int beg = b * CAP;
    int end = min(fill[b], beg + CAP);
    sm[threadIdx.x] = 0;
    __syncthreads();
    for (int i = beg + threadIdx.x; i < end; i += BROWS)
        atomicAdd(&sm[((unsigned)pcvp[i].x) >> 18], 1);
    __syncthreads();
    int c = sm[threadIdx.x];
    for (int off = 1; off < BROWS; off <<= 1) {
        int t = (threadIdx.x >= (unsigned)off) ? sm[threadIdx.x - off] : 0;
        __syncthreads();
        sm[threadIdx.x] += t;
        __syncthreads();
    }
    int eb = ebase[b];
    int excl = sm[threadIdx.x] - c;
    cur[threadIdx.x] = eb + excl;
    int node = b * BROWS + (int)threadIdx.x;
    if (node < N_NODES) rowptr[node] = eb + excl;
    __syncthreads();
    for (int i = beg + threadIdx.x; i < end; i += BROWS) {
        int2 p = pcvp[i];
        int rl = ((unsigned)p.x) >> 18;
        int pos = atomicAdd(&cur[rl], 1);
        cv[pos] = make_int2(p.x & COLMASK, p.y);
    }
}

// ---------------------------------------------------------------------------
// CSR SpMM: one wave per row, lane = dim. Staged UNR-deep chunks: all cv
// (scalar) loads and all x gathers issued before the FMA pass -> UNR gathers
// in flight per wave. Fused acc update (+ final scale).
// ---------------------------------------------------------------------------
template <bool WRITE_EGO>
__global__ __launch_bounds__(256) void lgcn_spmm_csr(
        const int* __restrict__ rowptr, const int2* __restrict__ cv,
        const float* __restrict__ x, float* __restrict__ ego_out,
        float* __restrict__ acc, float scale) {
    int row = blockIdx.x * (blockDim.x >> 6) + (threadIdx.x >> 6);
    row = __builtin_amdgcn_readfirstlane(row);   // wave-uniform -> scalar loads
    if (row >= N_NODES) return;
    int lane = threadIdx.x & 63;
    int beg = rowptr[row];
    int end = rowptr[row + 1];
    int lim = end - 1;
    float s = 0.f;
    for (int e = beg; e < end; e += UNR) {
        float xv[UNR];
        float vv[UNR];
#pragma unroll
        for (int k = 0; k < UNR; ++k) {
            int2 p = cv[min(e + k, lim)];
            xv[k] = x[(size_t)p.x * EMBED + lane];
            vv[k] = (e + k <= lim) ? __int_as_float(p.y) : 0.f;
        }
#pragma unroll
        for (int k = 0; k < UNR; ++k) s += vv[k] * xv[k];
    }
    size_t o = (size_t)row * EMBED + lane;
    if (WRITE_EGO) ego_out[o] = s;
    acc[o] = (acc[o] + s) * scale;
}

extern "C" void kernel_launch(void* const* d_in, const int* in_sizes, int n_in,
                              void* d_out, int out_size, void* d_ws, size_t ws_size,
                              hipStream_t stream) {
    const int*   rows = (const int*)d_in[0];
    const int*   cols = (const int*)d_in[1];
    const float* vals = (const float*)d_in[2];
    const float* u    = (const float*)d_in[3];
    const float* it   = (const float*)d_in[4];
    const float* up   = (const float*)d_in[5];
    const float* ip   = (const float*)d_in[6];
    const int nnz = in_sizes[0];

    float* acc = (float*)d_out;

    // workspace layout (~159 MB)
    float* ego0   = (float*)d_ws;                               // 38.4 MB
    float* ego1   = ego0 + (size_t)N_NODES * EMBED;             // 38.4 MB
    int2*  cv     = (int2*)(ego1 + (size_t)N_NODES * EMBED);    // nnz*8 = 38.4 MB
    int2*  pcvp   = cv + nnz;                                   // NB*CAP*8 = 43.2 MB
    int*   fill   = (int*)(pcvp + (size_t)NB * CAP);            // NB
    int*   ebase  = fill + NB;                                  // NB
    int*   rowptr = ebase + NB;                                 // N_NODES+1

    const int tpb = 256;
    const int totalVec = N_NODES * EMBED / 4;

    lgcn_init<<<(totalVec + tpb - 1) / tpb, tpb, 0, stream>>>(u, it, up, ip, ego0, acc);
    lgcn_fill_init<<<(NB + tpb - 1) / tpb, tpb, 0, stream>>>(fill);
    lgcn_partition<<<(nnz + PCHUNK - 1) / PCHUNK, tpb, 0, stream>>>(
        rows, cols, vals, fill, pcvp, nnz);
    lgcn_ebase<<<1, 1024, 0, stream>>>(fill, ebase, rowptr, nnz);
    lgcn_bsort<<<NB, BROWS, 0, stream>>>(pcvp, fill, ebase, rowptr, cv);

    const int rowsPerBlock = tpb / 64;
    const int spmmBlocks = (N_NODES + rowsPerBlock - 1) / rowsPerBlock;

    lgcn_spmm_csr<true><<<spmmBlocks, tpb, 0, stream>>>(rowptr, cv, ego0, ego1, acc, 1.0f);
    lgcn_spmm_csr<true><<<spmmBlocks, tpb, 0, stream>>>(rowptr, cv, ego1, ego0, acc, 1.0f);
    lgcn_spmm_csr<false><<<spmmBlocks, tpb, 0, stream>>>(rowptr, cv, ego0, nullptr, acc,
                                                         1.0f / (N_LAYERS + 1));
}

// Round 9
// 606.091 us; speedup vs baseline: 1.2136x; 1.1826x over previous
//
#include <hip/hip_runtime.h>

#define N_USERS 100000
#define N_ITEMS 50000
#define N_NODES 150000
#define EMBED 64
#define N_LAYERS 3

#define BSH 8                                   // log2(rows per bucket)
#define BROWS 256                               // rows per bucket
#define NB ((N_NODES + BROWS - 1) / BROWS)      // 586 buckets
#define CAP 9216                                // mean 8192 + ~11 sigma
#define PCHUNK 4096                             // edges per partition WG
#define COLMASK 0x3FFFF                         // 18 bits for col (N_NODES<2^18)
#define UNR 16                                  // gathers in flight per wave

// float -> bf16 (round-to-nearest-even), bf16 -> float
__device__ __forceinline__ unsigned short f2bf(float f) {
    unsigned u = __float_as_uint(f);
    return (unsigned short)((u + 0x7FFFu + ((u >> 16) & 1u)) >> 16);
}
__device__ __forceinline__ float bf2f(unsigned short h) {
    return __uint_as_float(((unsigned)h) << 16);
}

// ---------------------------------------------------------------------------
// init: ego0(bf16) = concat(u+u_pre, i+i_pre); acc(fp32) = same values
// ---------------------------------------------------------------------------
__global__ void lgcn_init(const float* __restrict__ u, const float* __restrict__ it,
                          const float* __restrict__ up, const float* __restrict__ ip,
                          unsigned short* __restrict__ egoh, float* __restrict__ acc) {
    int idx = blockIdx.x * blockDim.x + threadIdx.x;  // float4 index
    const int total = N_NODES * EMBED / 4;
    if (idx >= total) return;
    const int uCount = N_USERS * EMBED / 4;
    float4 v;
    if (idx < uCount) {
        float4 a = reinterpret_cast<const float4*>(u)[idx];
        float4 b = reinterpret_cast<const float4*>(up)[idx];
        v = make_float4(a.x + b.x, a.y + b.y, a.z + b.z, a.w + b.w);
    } else {
        int j = idx - uCount;
        float4 a = reinterpret_cast<const float4*>(it)[j];
        float4 b = reinterpret_cast<const float4*>(ip)[j];
        v = make_float4(a.x + b.x, a.y + b.y, a.z + b.z, a.w + b.w);
    }
    reinterpret_cast<float4*>(acc)[idx] = v;
    ushort4 h;
    h.x = f2bf(v.x); h.y = f2bf(v.y); h.z = f2bf(v.z); h.w = f2bf(v.w);
    reinterpret_cast<ushort4*>(egoh)[idx] = h;
}

// ---------------------------------------------------------------------------
// cursor init: fill[b] = b * CAP
// ---------------------------------------------------------------------------
__global__ void lgcn_fill_init(int* __restrict__ fill) {
    int b = blockIdx.x * blockDim.x + threadIdx.x;
    if (b < NB) fill[b] = b * CAP;
}

// ---------------------------------------------------------------------------
// partition: scatter edges into fixed-capacity bucket regions of pcvp,
// packed int2{ (rowLocal<<18)|col , bits(val) }.
// ---------------------------------------------------------------------------
__global__ void lgcn_partition(const int* __restrict__ rows, const int* __restrict__ cols,
                               const float* __restrict__ vals, int* __restrict__ fill,
                               int2* __restrict__ pcvp, int nnz) {
    __shared__ int lcnt[NB];
    __shared__ int lbase[NB];
    int c0 = blockIdx.x * PCHUNK;
    int cend = min(c0 + PCHUNK, nnz);
    for (int b = threadIdx.x; b < NB; b += blockDim.x) lcnt[b] = 0;
    __syncthreads();
    for (int e = c0 + threadIdx.x; e < cend; e += blockDim.x)
        atomicAdd(&lcnt[rows[e] >> BSH], 1);
    __syncthreads();
    for (int b = threadIdx.x; b < NB; b += blockDim.x) {
        int c = lcnt[b];
        lbase[b] = c ? atomicAdd(&fill[b], c) : 0;
        lcnt[b] = 0;  // reuse as intra-WG cursor
    }
    __syncthreads();
    for (int e = c0 + threadIdx.x; e < cend; e += blockDim.x) {
        int r = rows[e];
        int b = r >> BSH;
        int pos = lbase[b] + atomicAdd(&lcnt[b], 1);
        pos = min(pos, (b + 1) * CAP - 1);  // memory-safety clamp (never hit)
        pcvp[pos] = make_int2(((r & (BROWS - 1)) << 18) | cols[e], __float_as_int(vals[e]));
    }
}

// ---------------------------------------------------------------------------
// ebase: exclusive scan of realized bucket counts -> global edge base.
// ---------------------------------------------------------------------------
__global__ __launch_bounds__(1024) void lgcn_ebase(const int* __restrict__ fill,
                                                   int* __restrict__ ebase,
                                                   int* __restrict__ rowptr, int nnz) {
    __shared__ int sm[1024];
    int c = (threadIdx.x < NB) ? (fill[threadIdx.x] - threadIdx.x * CAP) : 0;
    sm[threadIdx.x] = c;
    __syncthreads();
    for (int off = 1; off < 1024; off <<= 1) {
        int t = (threadIdx.x >= (unsigned)off) ? sm[threadIdx.x - off] : 0;
        __syncthreads();
        sm[threadIdx.x] += t;
        __syncthreads();
    }
    if (threadIdx.x < NB) ebase[threadIdx.x] = sm[threadIdx.x] - c;
    if (threadIdx.x == 0) rowptr[N_NODES] = nnz;
}

// ---------------------------------------------------------------------------
// bsort: one WG per 256-row bucket; LDS hist + scan -> rowptr; scatter
// (col,val) to exact row-sorted positions.
// ---------------------------------------------------------------------------
__global__ __launch_bounds__(BROWS) void lgcn_bsort(const int2* __restrict__ pcvp,
                                                    const int* __restrict__ fill,
                                                    const int* __restrict__ ebase,
                                                    int* __restrict__ rowptr,
                                                    int2* __restrict__ cv) {
    __shared__ int sm[BROWS];
    __shared__ int cur[BROWS];
    int b = blockIdx.x;
    int beg = b * CAP;
    int end = min(fill[b], beg + CAP);
    sm[threadIdx.x] = 0;
    __syncthreads();
    for (int i = beg + threadIdx.x; i < end; i += BROWS)
        atomicAdd(&sm[((unsigned)pcvp[i].x) >> 18], 1);
    __syncthreads();
    int c = sm[threadIdx.x];
    for (int off = 1; off < BROWS; off <<= 1) {
        int t = (threadIdx.x >= (unsigned)off) ? sm[threadIdx.x - off] : 0;
        __syncthreads();
        sm[threadIdx.x] += t;
        __syncthreads();
    }
    int eb = ebase[b];
    int excl = sm[threadIdx.x] - c;
    cur[threadIdx.x] = eb + excl;
    int node = b * BROWS + (int)threadIdx.x;
    if (node < N_NODES) rowptr[node] = eb + excl;
    __syncthreads();
    for (int i = beg + threadIdx.x; i < end; i += BROWS) {
        int2 p = pcvp[i];
        int rl = ((unsigned)p.x) >> 18;
        int pos = atomicAdd(&cur[rl], 1);
        cv[pos] = make_int2(p.x & COLMASK, p.y);
    }
}

// ---------------------------------------------------------------------------
// CSR SpMM: one wave per row, lane = dim. Gather operand x is bf16 (128 B
// per row) -> half the L2/fabric bytes of fp32. fp32 accumulate; writes
// bf16 ego for the next layer + fp32 acc update (+ final scale).
// ---------------------------------------------------------------------------
template <bool WRITE_EGO>
__global__ __launch_bounds__(256) void lgcn_spmm_csr(
        const int* __restrict__ rowptr, const int2* __restrict__ cv,
        const unsigned short* __restrict__ x, unsigned short* __restrict__ ego_out,
        float* __restrict__ acc, float scale) {
    int row = blockIdx.x * (blockDim.x >> 6) + (threadIdx.x >> 6);
    row = __builtin_amdgcn_readfirstlane(row);   // wave-uniform -> scalar loads
    if (row >= N_NODES) return;
    int lane = threadIdx.x & 63;
    int beg = rowptr[row];
    int end = rowptr[row + 1];
    int lim = end - 1;
    float s = 0.f;
    for (int e = beg; e < end; e += UNR) {
        unsigned short xh[UNR];
        float vv[UNR];
#pragma unroll
        for (int k = 0; k < UNR; ++k) {
            int2 p = cv[min(e + k, lim)];
            xh[k] = x[(size_t)p.x * EMBED + lane];
            vv[k] = (e + k <= lim) ? __int_as_float(p.y) : 0.f;
        }
#pragma unroll
        for (int k = 0; k < UNR; ++k) s += vv[k] * bf2f(xh[k]);
    }
    size_t o = (size_t)row * EMBED + lane;
    if (WRITE_EGO) ego_out[o] = f2bf(s);
    acc[o] = (acc[o] + s) * scale;
}

extern "C" void kernel_launch(void* const* d_in, const int* in_sizes, int n_in,
                              void* d_out, int out_size, void* d_ws, size_t ws_size,
                              hipStream_t stream) {
    const int*   rows = (const int*)d_in[0];
    const int*   cols = (const int*)d_in[1];
    const float* vals = (const float*)d_in[2];
    const float* u    = (const float*)d_in[3];
    const float* it   = (const float*)d_in[4];
    const float* up   = (const float*)d_in[5];
    const float* ip   = (const float*)d_in[6];
    const int nnz = in_sizes[0];

    float* acc = (float*)d_out;

    // workspace layout (~122 MB)
    unsigned short* egoh0 = (unsigned short*)d_ws;                    // 19.2 MB
    unsigned short* egoh1 = egoh0 + (size_t)N_NODES * EMBED;          // 19.2 MB
    int2*  cv     = (int2*)(egoh1 + (size_t)N_NODES * EMBED);         // nnz*8 = 38.4 MB
    int2*  pcvp   = cv + nnz;                                         // NB*CAP*8 = 43.2 MB
    int*   fill   = (int*)(pcvp + (size_t)NB * CAP);                  // NB
    int*   ebase  = fill + NB;                                        // NB
    int*   rowptr = ebase + NB;                                       // N_NODES+1

    const int tpb = 256;
    const int totalVec = N_NODES * EMBED / 4;

    lgcn_init<<<(totalVec + tpb - 1) / tpb, tpb, 0, stream>>>(u, it, up, ip, egoh0, acc);
    lgcn_fill_init<<<(NB + tpb - 1) / tpb, tpb, 0, stream>>>(fill);
    lgcn_partition<<<(nnz + PCHUNK - 1) / PCHUNK, tpb, 0, stream>>>(
        rows, cols, vals, fill, pcvp, nnz);
    lgcn_ebase<<<1, 1024, 0, stream>>>(fill, ebase, rowptr, nnz);
    lgcn_bsort<<<NB, BROWS, 0, stream>>>(pcvp, fill, ebase, rowptr, cv);

    const int rowsPerBlock = tpb / 64;
    const int spmmBlocks = (N_NODES + rowsPerBlock - 1) / rowsPerBlock;

    lgcn_spmm_csr<true><<<spmmBlocks, tpb, 0, stream>>>(rowptr, cv, egoh0, egoh1, acc, 1.0f);
    lgcn_spmm_csr<true><<<spmmBlocks, tpb, 0, stream>>>(rowptr, cv, egoh1, egoh0, acc, 1.0f);
    lgcn_spmm_csr<false><<<spmmBlocks, tpb, 0, stream>>>(rowptr, cv, egoh0, nullptr, acc,
                                                         1.0f / (N_LAYERS + 1));
}

// Round 10
// 542.302 us; speedup vs baseline: 1.3564x; 1.1176x over previous
//
#include <hip/hip_runtime.h>

#define N_USERS 100000
#define N_ITEMS 50000
#define N_NODES 150000
#define EMBED 64
#define N_LAYERS 3

#define BSH 8                                   // log2(rows per bucket)
#define BROWS 256                               // rows per bucket
#define NB ((N_NODES + BROWS - 1) / BROWS)      // 586 buckets
#define CAP 9216                                // mean 8192 + ~11 sigma
#define PCHUNK 4096                             // edges per partition WG
#define COLMASK 0x3FFFF                         // 18 bits for col (N_NODES<2^18)
#define C 8                                     // pipeline chunk (gathers in flight)

// float -> bf16 (round-to-nearest-even), bf16 -> float
__device__ __forceinline__ unsigned short f2bf(float f) {
    unsigned u = __float_as_uint(f);
    return (unsigned short)((u + 0x7FFFu + ((u >> 16) & 1u)) >> 16);
}
__device__ __forceinline__ float bf2f(unsigned short h) {
    return __uint_as_float(((unsigned)h) << 16);
}

// ---------------------------------------------------------------------------
// init: ego0(bf16) = concat(u+u_pre, i+i_pre); acc(fp32) = same values
// ---------------------------------------------------------------------------
__global__ void lgcn_init(const float* __restrict__ u, const float* __restrict__ it,
                          const float* __restrict__ up, const float* __restrict__ ip,
                          unsigned short* __restrict__ egoh, float* __restrict__ acc) {
    int idx = blockIdx.x * blockDim.x + threadIdx.x;  // float4 index
    const int total = N_NODES * EMBED / 4;
    if (idx >= total) return;
    const int uCount = N_USERS * EMBED / 4;
    float4 v;
    if (idx < uCount) {
        float4 a = reinterpret_cast<const float4*>(u)[idx];
        float4 b = reinterpret_cast<const float4*>(up)[idx];
        v = make_float4(a.x + b.x, a.y + b.y, a.z + b.z, a.w + b.w);
    } else {
        int j = idx - uCount;
        float4 a = reinterpret_cast<const float4*>(it)[j];
        float4 b = reinterpret_cast<const float4*>(ip)[j];
        v = make_float4(a.x + b.x, a.y + b.y, a.z + b.z, a.w + b.w);
    }
    reinterpret_cast<float4*>(acc)[idx] = v;
    ushort4 h;
    h.x = f2bf(v.x); h.y = f2bf(v.y); h.z = f2bf(v.z); h.w = f2bf(v.w);
    reinterpret_cast<ushort4*>(egoh)[idx] = h;
}

// ---------------------------------------------------------------------------
// cursor init: fill[b] = b * CAP
// ---------------------------------------------------------------------------
__global__ void lgcn_fill_init(int* __restrict__ fill) {
    int b = blockIdx.x * blockDim.x + threadIdx.x;
    if (b < NB) fill[b] = b * CAP;
}

// ---------------------------------------------------------------------------
// partition: scatter edges into fixed-capacity bucket regions of pcvp,
// packed int2{ (rowLocal<<18)|col , bits(val) }.
// ---------------------------------------------------------------------------
__global__ void lgcn_partition(const int* __restrict__ rows, const int* __restrict__ cols,
                               const float* __restrict__ vals, int* __restrict__ fill,
                               int2* __restrict__ pcvp, int nnz) {
    __shared__ int lcnt[NB];
    __shared__ int lbase[NB];
    int c0 = blockIdx.x * PCHUNK;
    int cend = min(c0 + PCHUNK, nnz);
    for (int b = threadIdx.x; b < NB; b += blockDim.x) lcnt[b] = 0;
    __syncthreads();
    for (int e = c0 + threadIdx.x; e < cend; e += blockDim.x)
        atomicAdd(&lcnt[rows[e] >> BSH], 1);
    __syncthreads();
    for (int b = threadIdx.x; b < NB; b += blockDim.x) {
        int c = lcnt[b];
        lbase[b] = c ? atomicAdd(&fill[b], c) : 0;
        lcnt[b] = 0;  // reuse as intra-WG cursor
    }
    __syncthreads();
    for (int e = c0 + threadIdx.x; e < cend; e += blockDim.x) {
        int r = rows[e];
        int b = r >> BSH;
        int pos = lbase[b] + atomicAdd(&lcnt[b], 1);
        pos = min(pos, (b + 1) * CAP - 1);  // memory-safety clamp (never hit)
        pcvp[pos] = make_int2(((r & (BROWS - 1)) << 18) | cols[e], __float_as_int(vals[e]));
    }
}

// ---------------------------------------------------------------------------
// ebase: exclusive scan of realized bucket counts -> global edge base.
// ---------------------------------------------------------------------------
__global__ __launch_bounds__(1024) void lgcn_ebase(const int* __restrict__ fill,
                                                   int* __restrict__ ebase,
                                                   int* __restrict__ rowptr, int nnz) {
    __shared__ int sm[1024];
    int c = (threadIdx.x < NB) ? (fill[threadIdx.x] - threadIdx.x * CAP) : 0;
    sm[threadIdx.x] = c;
    __syncthreads();
    for (int off = 1; off < 1024; off <<= 1) {
        int t = (threadIdx.x >= (unsigned)off) ? sm[threadIdx.x - off] : 0;
        __syncthreads();
        sm[threadIdx.x] += t;
        __syncthreads();
    }
    if (threadIdx.x < NB) ebase[threadIdx.x] = sm[threadIdx.x] - c;
    if (threadIdx.x == 0) rowptr[N_NODES] = nnz;
}

// ---------------------------------------------------------------------------
// bsort: one WG per 256-row bucket; LDS hist + scan -> rowptr; scatter
// (col,val) to exact row-sorted positions.
// ---------------------------------------------------------------------------
__global__ __launch_bounds__(BROWS) void lgcn_bsort(const int2* __restrict__ pcvp,
                                                    const int* __restrict__ fill,
                                                    const int* __restrict__ ebase,
                                                    int* __restrict__ rowptr,
                                                    int2* __restrict__ cv) {
    __shared__ int sm[BROWS];
    __shared__ int cur[BROWS];
    int b = blockIdx.x;
    int beg = b * CAP;
    int end = min(fill[b], beg + CAP);
    sm[threadIdx.x] = 0;
    __syncthreads();
    for (int i = beg + threadIdx.x; i < end; i += BROWS)
        atomicAdd(&sm[((unsigned)pcvp[i].x) >> 18], 1);
    __syncthreads();
    int c = sm[threadIdx.x];
    for (int off = 1; off < BROWS; off <<= 1) {
        int t = (threadIdx.x >= (unsigned)off) ? sm[threadIdx.x - off] : 0;
        __syncthreads();
        sm[threadIdx.x] += t;
        __syncthreads();
    }
    int eb = ebase[b];
    int excl = sm[threadIdx.x] - c;
    cur[threadIdx.x] = eb + excl;
    int node = b * BROWS + (int)threadIdx.x;
    if (node < N_NODES) rowptr[node] = eb + excl;
    __syncthreads();
    for (int i = beg + threadIdx.x; i < end; i += BROWS) {
        int2 p = pcvp[i];
        int rl = ((unsigned)p.x) >> 18;
        int pos = atomicAdd(&cur[rl], 1);
        cv[pos] = make_int2(p.x & COLMASK, p.y);
    }
}

// ---------------------------------------------------------------------------
// CSR SpMM: one wave per row, lane = dim, bf16 gather operand.
// Explicit two-stage software pipeline (chunk = C edges): chunk B's cv loads
// + gathers are issued BEFORE chunk A's FMA pass, and B's first use (the
// rotate) sits after the FMAs -> C gathers stay in flight per wave.
// Accumulation order over edges identical to round 9 (bit-identical output).
// ---------------------------------------------------------------------------
template <bool WRITE_EGO>
__global__ __launch_bounds__(256) void lgcn_spmm_csr(
        const int* __restrict__ rowptr, const int2* __restrict__ cv,
        const unsigned short* __restrict__ x, unsigned short* __restrict__ ego_out,
        float* __restrict__ acc, float scale) {
    int row = blockIdx.x * (blockDim.x >> 6) + (threadIdx.x >> 6);
    row = __builtin_amdgcn_readfirstlane(row);   // wave-uniform -> scalar loads
    if (row >= N_NODES) return;
    int lane = threadIdx.x & 63;
    int beg = rowptr[row];
    int end = rowptr[row + 1];
    float s = 0.f;
    if (beg < end) {
        int lim = end - 1;
        float va[C]; unsigned short xa[C];
#pragma unroll
        for (int k = 0; k < C; ++k) {
            int2 p = cv[min(beg + k, lim)];
            xa[k] = x[(unsigned)p.x * 64u + (unsigned)lane];
            va[k] = (beg + k <= lim) ? __int_as_float(p.y) : 0.f;
        }
        for (int e = beg + C; e < end; e += C) {
            float vb[C]; unsigned short xb[C];
#pragma unroll
            for (int k = 0; k < C; ++k) {
                int2 p = cv[min(e + k, lim)];
                xb[k] = x[(unsigned)p.x * 64u + (unsigned)lane];
                vb[k] = (e + k <= lim) ? __int_as_float(p.y) : 0.f;
            }
#pragma unroll
            for (int k = 0; k < C; ++k) s += va[k] * bf2f(xa[k]);
#pragma unroll
            for (int k = 0; k < C; ++k) { va[k] = vb[k]; xa[k] = xb[k]; }
        }
#pragma unroll
        for (int k = 0; k < C; ++k) s += va[k] * bf2f(xa[k]);
    }
    size_t o = (size_t)row * EMBED + lane;
    if (WRITE_EGO) ego_out[o] = f2bf(s);
    acc[o] = (acc[o] + s) * scale;
}

extern "C" void kernel_launch(void* const* d_in, const int* in_sizes, int n_in,
                              void* d_out, int out_size, void* d_ws, size_t ws_size,
                              hipStream_t stream) {
    const int*   rows = (const int*)d_in[0];
    const int*   cols = (const int*)d_in[1];
    const float* vals = (const float*)d_in[2];
    const float* u    = (const float*)d_in[3];
    const float* it   = (const float*)d_in[4];
    const float* up   = (const float*)d_in[5];
    const float* ip   = (const float*)d_in[6];
    const int nnz = in_sizes[0];

    float* acc = (float*)d_out;

    // workspace layout (~122 MB)
    unsigned short* egoh0 = (unsigned short*)d_ws;                    // 19.2 MB
    unsigned short* egoh1 = egoh0 + (size_t)N_NODES * EMBED;          // 19.2 MB
    int2*  cv     = (int2*)(egoh1 + (size_t)N_NODES * EMBED);         // nnz*8 = 38.4 MB
    int2*  pcvp   = cv + nnz;                                         // NB*CAP*8 = 43.2 MB
    int*   fill   = (int*)(pcvp + (size_t)NB * CAP);                  // NB
    int*   ebase  = fill + NB;                                        // NB
    int*   rowptr = ebase + NB;                                       // N_NODES+1

    const int tpb = 256;
    const int totalVec = N_NODES * EMBED / 4;

    lgcn_init<<<(totalVec + tpb - 1) / tpb, tpb, 0, stream>>>(u, it, up, ip, egoh0, acc);
    lgcn_fill_init<<<(NB + tpb - 1) / tpb, tpb, 0, stream>>>(fill);
    lgcn_partition<<<(nnz + PCHUNK - 1) / PCHUNK, tpb, 0, stream>>>(
        rows, cols, vals, fill, pcvp, nnz);
    lgcn_ebase<<<1, 1024, 0, stream>>>(fill, ebase, rowptr, nnz);
    lgcn_bsort<<<NB, BROWS, 0, stream>>>(pcvp, fill, ebase, rowptr, cv);

    const int rowsPerBlock = tpb / 64;
    const int spmmBlocks = (N_NODES + rowsPerBlock - 1) / rowsPerBlock;

    lgcn_spmm_csr<true><<<spmmBlocks, tpb, 0, stream>>>(rowptr, cv, egoh0, egoh1, acc, 1.0f);
    lgcn_spmm_csr<true><<<spmmBlocks, tpb, 0, stream>>>(rowptr, cv, egoh1, egoh0, acc, 1.0f);
    lgcn_spmm_csr<false><<<spmmBlocks, tpb, 0, stream>>>(rowptr, cv, egoh0, nullptr, acc,
                                                         1.0f / (N_LAYERS + 1));
}

// Round 11
// 533.374 us; speedup vs baseline: 1.3791x; 1.0167x over previous
//
#include <hip/hip_runtime.h>

#define N_USERS 100000
#define N_ITEMS 50000
#define N_NODES 150000
#define EMBED 64
#define N_LAYERS 3

#define BSH 8                                   // log2(rows per bucket)
#define BROWS 256                               // rows per bucket
#define NB ((N_NODES + BROWS - 1) / BROWS)      // 586 buckets
#define PCHUNK 4096                             // edges per partition WG
#define COLMASK 0x3FFFF                         // 18 bits for col (N_NODES<2^18)
#define C 8                                     // spmm pipeline chunk (gathers in flight)

// float -> bf16 (round-to-nearest-even), bf16 -> float
__device__ __forceinline__ unsigned short f2bf(float f) {
    unsigned u = __float_as_uint(f);
    return (unsigned short)((u + 0x7FFFu + ((u >> 16) & 1u)) >> 16);
}
__device__ __forceinline__ float bf2f(unsigned short h) {
    return __uint_as_float(((unsigned)h) << 16);
}

// ---------------------------------------------------------------------------
// init: ego0(bf16) = concat(u+u_pre, i+i_pre); acc(fp32) = same values
// ---------------------------------------------------------------------------
__global__ void lgcn_init(const float* __restrict__ u, const float* __restrict__ it,
                          const float* __restrict__ up, const float* __restrict__ ip,
                          unsigned short* __restrict__ egoh, float* __restrict__ acc) {
    int idx = blockIdx.x * blockDim.x + threadIdx.x;  // float4 index
    const int total = N_NODES * EMBED / 4;
    if (idx >= total) return;
    const int uCount = N_USERS * EMBED / 4;
    float4 v;
    if (idx < uCount) {
        float4 a = reinterpret_cast<const float4*>(u)[idx];
        float4 b = reinterpret_cast<const float4*>(up)[idx];
        v = make_float4(a.x + b.x, a.y + b.y, a.z + b.z, a.w + b.w);
    } else {
        int j = idx - uCount;
        float4 a = reinterpret_cast<const float4*>(it)[j];
        float4 b = reinterpret_cast<const float4*>(ip)[j];
        v = make_float4(a.x + b.x, a.y + b.y, a.z + b.z, a.w + b.w);
    }
    reinterpret_cast<float4*>(acc)[idx] = v;
    ushort4 h;
    h.x = f2bf(v.x); h.y = f2bf(v.y); h.z = f2bf(v.z); h.w = f2bf(v.w);
    reinterpret_cast<ushort4*>(egoh)[idx] = h;
}

// ---------------------------------------------------------------------------
// pass A: per-WG bucket histogram -> Cmat[wg][b]  (no global atomics)
// ---------------------------------------------------------------------------
__global__ void lgcn_cnt(const int* __restrict__ rows, int* __restrict__ Cmat, int nnz) {
    __shared__ int lcnt[NB];
    int wg = blockIdx.x;
    int c0 = wg * PCHUNK;
    int cend = min(c0 + PCHUNK, nnz);
    for (int b = threadIdx.x; b < NB; b += blockDim.x) lcnt[b] = 0;
    __syncthreads();
    for (int e = c0 + threadIdx.x; e < cend; e += blockDim.x)
        atomicAdd(&lcnt[rows[e] >> BSH], 1);
    __syncthreads();
    for (int b = threadIdx.x; b < NB; b += blockDim.x)
        Cmat[(size_t)wg * NB + b] = lcnt[b];
}

// ---------------------------------------------------------------------------
// colscan: one block per bucket b; exclusive scan of Cmat[:,b] over nwg WGs
// (in-place) + column total.
// ---------------------------------------------------------------------------
__global__ __launch_bounds__(256) void lgcn_colscan(int* __restrict__ Cmat,
                                                    int* __restrict__ colTotal, int nwg) {
    __shared__ int sm[256];
    int b = blockIdx.x;
    int carry = 0;
    for (int c0 = 0; c0 < nwg; c0 += 256) {
        int wg = c0 + threadIdx.x;
        int v = (wg < nwg) ? Cmat[(size_t)wg * NB + b] : 0;
        sm[threadIdx.x] = v;
        __syncthreads();
        for (int off = 1; off < 256; off <<= 1) {
            int t = (threadIdx.x >= (unsigned)off) ? sm[threadIdx.x - off] : 0;
            __syncthreads();
            sm[threadIdx.x] += t;
            __syncthreads();
        }
        if (wg < nwg) Cmat[(size_t)wg * NB + b] = carry + sm[threadIdx.x] - v;
        carry += sm[255];
        __syncthreads();
    }
    if (threadIdx.x == 0) colTotal[b] = carry;
}

// ---------------------------------------------------------------------------
// btscan: exclusive scan of colTotal -> bucketBase[NB+1]; sentinels.
// ---------------------------------------------------------------------------
__global__ __launch_bounds__(1024) void lgcn_btscan(const int* __restrict__ colTotal,
                                                    int* __restrict__ bucketBase,
                                                    int* __restrict__ rowptr, int nnz) {
    __shared__ int sm[1024];
    int c = (threadIdx.x < NB) ? colTotal[threadIdx.x] : 0;
    sm[threadIdx.x] = c;
    __syncthreads();
    for (int off = 1; off < 1024; off <<= 1) {
        int t = (threadIdx.x >= (unsigned)off) ? sm[threadIdx.x - off] : 0;
        __syncthreads();
        sm[threadIdx.x] += t;
        __syncthreads();
    }
    if (threadIdx.x < NB) bucketBase[threadIdx.x] = sm[threadIdx.x] - c;
    if (threadIdx.x == 0) { bucketBase[NB] = nnz; rowptr[N_NODES] = nnz; }
}

// ---------------------------------------------------------------------------
// pass B: deterministic scatter. LDS cursors = bucketBase[b] + Cmat[wg][b];
// zero global atomics; dense output (no CAP gaps).
// packed int2{ (rowLocal<<18)|col , bits(val) }.
// ---------------------------------------------------------------------------
__global__ void lgcn_scatter(const int* __restrict__ rows, const int* __restrict__ cols,
                             const float* __restrict__ vals, const int* __restrict__ Cmat,
                             const int* __restrict__ bucketBase, int2* __restrict__ pcvp,
                             int nnz) {
    __shared__ int cur[NB];
    int wg = blockIdx.x;
    int c0 = wg * PCHUNK;
    int cend = min(c0 + PCHUNK, nnz);
    for (int b = threadIdx.x; b < NB; b += blockDim.x)
        cur[b] = bucketBase[b] + Cmat[(size_t)wg * NB + b];
    __syncthreads();
    for (int e = c0 + threadIdx.x; e < cend; e += blockDim.x) {
        int r = rows[e];
        int b = r >> BSH;
        int pos = atomicAdd(&cur[b], 1);
        pcvp[pos] = make_int2(((r & (BROWS - 1)) << 18) | cols[e], __float_as_int(vals[e]));
    }
}

// ---------------------------------------------------------------------------
// bsort: one WG per 256-row bucket; LDS hist + scan -> rowptr; scatter
// (col,val) to exact row-sorted positions. Dense input ranges.
// ---------------------------------------------------------------------------
__global__ __launch_bounds__(BROWS) void lgcn_bsort(const int2* __restrict__ pcvp,
                                                    const int* __restrict__ bucketBase,
                                                    int* __restrict__ rowptr,
                                                    int2* __restrict__ cv) {
    __shared__ int sm[BROWS];
    __shared__ int cur[BROWS];
    int b = blockIdx.x;
    int beg = bucketBase[b];
    int end = bucketBase[b + 1];
    sm[threadIdx.x] = 0;
    __syncthreads();
    for (int i = beg + threadIdx.x; i < end; i += BROWS)
        atomicAdd(&sm[((unsigned)pcvp[i].x) >> 18], 1);
    __syncthreads();
    int c = sm[threadIdx.x];
    for (int off = 1; off < BROWS; off <<= 1) {
        int t = (threadIdx.x >= (unsigned)off) ? sm[threadIdx.x - off] : 0;
        __syncthreads();
        sm[threadIdx.x] += t;
        __syncthreads();
    }
    int excl = sm[threadIdx.x] - c;
    cur[threadIdx.x] = beg + excl;
    int node = b * BROWS + (int)threadIdx.x;
    if (node < N_NODES) rowptr[node] = beg + excl;
    __syncthreads();
    for (int i = beg + threadIdx.x; i < end; i += BROWS) {
        int2 p = pcvp[i];
        int rl = ((unsigned)p.x) >> 18;
        int pos = atomicAdd(&cur[rl], 1);
        cv[pos] = make_int2(p.x & COLMASK, p.y);
    }
}

// ---------------------------------------------------------------------------
// CSR SpMM: one wave per row, lane = dim, bf16 gather operand.
// Explicit two-stage software pipeline (chunk = C edges) keeps C gathers in
// flight per wave. Fused acc update (+ final scale).
// ---------------------------------------------------------------------------
template <bool WRITE_EGO>
__global__ __launch_bounds__(256) void lgcn_spmm_csr(
        const int* __restrict__ rowptr, const int2* __restrict__ cv,
        const unsigned short* __restrict__ x, unsigned short* __restrict__ ego_out,
        float* __restrict__ acc, float scale) {
    int row = blockIdx.x * (blockDim.x >> 6) + (threadIdx.x >> 6);
    row = __builtin_amdgcn_readfirstlane(row);   // wave-uniform -> scalar loads
    if (row >= N_NODES) return;
    int lane = threadIdx.x & 63;
    int beg = rowptr[row];
    int end = rowptr[row + 1];
    float s = 0.f;
    if (beg < end) {
        int lim = end - 1;
        float va[C]; unsigned short xa[C];
#pragma unroll
        for (int k = 0; k < C; ++k) {
            int2 p = cv[min(beg + k, lim)];
            xa[k] = x[(unsigned)p.x * 64u + (unsigned)lane];
            va[k] = (beg + k <= lim) ? __int_as_float(p.y) : 0.f;
        }
        for (int e = beg + C; e < end; e += C) {
            float vb[C]; unsigned short xb[C];
#pragma unroll
            for (int k = 0; k < C; ++k) {
                int2 p = cv[min(e + k, lim)];
                xb[k] = x[(unsigned)p.x * 64u + (unsigned)lane];
                vb[k] = (e + k <= lim) ? __int_as_float(p.y) : 0.f;
            }
#pragma unroll
            for (int k = 0; k < C; ++k) s += va[k] * bf2f(xa[k]);
#pragma unroll
            for (int k = 0; k < C; ++k) { va[k] = vb[k]; xa[k] = xb[k]; }
        }
#pragma unroll
        for (int k = 0; k < C; ++k) s += va[k] * bf2f(xa[k]);
    }
    size_t o = (size_t)row * EMBED + lane;
    if (WRITE_EGO) ego_out[o] = f2bf(s);
    acc[o] = (acc[o] + s) * scale;
}

extern "C" void kernel_launch(void* const* d_in, const int* in_sizes, int n_in,
                              void* d_out, int out_size, void* d_ws, size_t ws_size,
                              hipStream_t stream) {
    const int*   rows = (const int*)d_in[0];
    const int*   cols = (const int*)d_in[1];
    const float* vals = (const float*)d_in[2];
    const float* u    = (const float*)d_in[3];
    const float* it   = (const float*)d_in[4];
    const float* up   = (const float*)d_in[5];
    const float* ip   = (const float*)d_in[6];
    const int nnz = in_sizes[0];
    const int nwg = (nnz + PCHUNK - 1) / PCHUNK;

    float* acc = (float*)d_out;

    // workspace layout (~119 MB)
    unsigned short* egoh0 = (unsigned short*)d_ws;                    // 19.2 MB
    unsigned short* egoh1 = egoh0 + (size_t)N_NODES * EMBED;          // 19.2 MB
    int2*  cv         = (int2*)(egoh1 + (size_t)N_NODES * EMBED);     // nnz*8 = 38.4 MB
    int2*  pcvp       = cv + nnz;                                     // nnz*8 = 38.4 MB
    int*   Cmat       = (int*)(pcvp + nnz);                           // nwg*NB ints (~2.8 MB)
    int*   colTotal   = Cmat + (size_t)nwg * NB;                      // NB
    int*   bucketBase = colTotal + NB;                                // NB+1
    int*   rowptr     = bucketBase + NB + 1;                          // N_NODES+1

    const int tpb = 256;
    const int totalVec = N_NODES * EMBED / 4;

    lgcn_init<<<(totalVec + tpb - 1) / tpb, tpb, 0, stream>>>(u, it, up, ip, egoh0, acc);
    lgcn_cnt<<<nwg, tpb, 0, stream>>>(rows, Cmat, nnz);
    lgcn_colscan<<<NB, 256, 0, stream>>>(Cmat, colTotal, nwg);
    lgcn_btscan<<<1, 1024, 0, stream>>>(colTotal, bucketBase, rowptr, nnz);
    lgcn_scatter<<<nwg, tpb, 0, stream>>>(rows, cols, vals, Cmat, bucketBase, pcvp, nnz);
    lgcn_bsort<<<NB, BROWS, 0, stream>>>(pcvp, bucketBase, rowptr, cv);

    const int rowsPerBlock = tpb / 64;
    const int spmmBlocks = (N_NODES + rowsPerBlock - 1) / rowsPerBlock;

    lgcn_spmm_csr<true><<<spmmBlocks, tpb, 0, stream>>>(rowptr, cv, egoh0, egoh1, acc, 1.0f);
    lgcn_spmm_csr<true><<<spmmBlocks, tpb, 0, stream>>>(rowptr, cv, egoh1, egoh0, acc, 1.0f);
    lgcn_spmm_csr<false><<<spmmBlocks, tpb, 0, stream>>>(rowptr, cv, egoh0, nullptr, acc,
                                                         1.0f / (N_LAYERS + 1));
}